// Round 14
// baseline (357.313 us; speedup 1.0000x reference)
//
#include <hip/hip_runtime.h>
#include <hip/hip_bf16.h>

// B=4, N=1024, E=256, H=8, D=32. Float tensors may be bf16 OR fp32 in d_in /
// d_out (detected at runtime on-device); adj is int32.
// Output: x_out [4,1024,256] then e_out [4,1024,1024] (element offsets).
//
// ws float offsets:
//   [0 .. 196608)   : 6 weight matrices, transposed, bf16, quad-interleaved
//                     matrix m at ushort offset m*65536; element (e,o) at
//                     ((e>>2)*256 + o)*4 + (e&3).  m: 0=Wcat 1=LIN 2=WQ 3=WK 4=WV 5=WO
#define BIAS_OFF 196608   // lin_b, bq, bk, bv, bo, a1, a2  (7*256 fp32)
#define S1_OFF   198400   // [h][4096]
#define S2_OFF   231168
#define CS_OFF   263936   // 32768: column partial sums+sumsq (reused twice)
#define ST1_OFF  296704   // mean[1024] + inv[1024]
#define ST2_OFF  298752
#define A_OFF    300800   // WhT bf16 [h][b][d][n] (2 MB) -> later Q,o fp32 head-major
#define B_OFF    1349376  // 4 MB: rownorm(xa)     -> later K bf16 head-major [b][h][n][32]
#define C_OFF    2397952  // 4 MB: rownorm(lin)    -> later V^T bf16 head-major [b][h][d][n]
#define FLAG_F   3446528  // int: 1 = bf16 tensors, 0 = fp32 tensors
// end 3446529 floats = 13.8 MB

#define NEGC (-9.0e15f)

typedef __attribute__((ext_vector_type(8))) short bf16x8s;
typedef __attribute__((ext_vector_type(4))) float f32x4;

static __device__ __forceinline__ float bf2f(unsigned short u) {
  union { unsigned int i; float f; } v; v.i = ((unsigned int)u) << 16; return v.f;
}
static __device__ __forceinline__ unsigned short f2bf(float f) {
  union { float f; unsigned int u; } v; v.f = f;
  unsigned int r = (v.u + 0x7FFFu + ((v.u >> 16) & 1u)) >> 16;   // RNE
  return (unsigned short)r;
}
static __device__ __forceinline__ float ldin(const void* p, long i, int bf) {
  return bf ? bf2f(((const unsigned short*)p)[i]) : ((const float*)p)[i];
}
static __device__ __forceinline__ unsigned short rdbf(const void* p, long i, int bf) {
  if (bf) return ((const unsigned short*)p)[i];
  return f2bf(((const float*)p)[i]);
}
static __device__ __forceinline__ void stout(void* p, long i, float v, int bf) {
  if (bf) ((unsigned short*)p)[i] = f2bf(v);
  else    ((float*)p)[i] = v;
}

// ---------------- dtype detector -------------------------------------------
__global__ __launch_bounds__(64) void detect_kernel(const unsigned short* x, int* flag) {
  int lane = threadIdx.x;
  unsigned short u = x[2 * lane];
  int e = (u >> 7) & 0xFF;
  bool good = (e >= 100 && e <= 140);
  unsigned long long m = __ballot(good);
  if (lane == 0) *flag = (__popcll(m) >= 48) ? 1 : 0;
}

// ---------------- prep: weights -> transposed quad bf16; biases -> fp32 ----
__global__ __launch_bounds__(256) void prep_kernel(
    const void* wg, const void* lin_w, const void* inp_w, const void* out_w,
    const void* lin_b, const void* inp_b, const void* out_b,
    const void* a1, const void* a2, float* ws, const int* flagp) {
  const int bf = *flagp;
  unsigned short* wbf = (unsigned short*)ws;
  int t = threadIdx.x;
  int f = blockIdx.x;
  int m = blockIdx.y;
  int dst = m*65536 + ((f >> 2)*256 + t)*4 + (f & 3);
  if (m == 0) {
    int h = t >> 5, d = t & 31;
    wbf[dst] = rdbf(wg, h*8192 + f*32 + d, bf);
  } else if (m == 1) wbf[dst] = rdbf(lin_w, t*256 + f, bf);
  else if (m == 2)   wbf[dst] = rdbf(inp_w, t*256 + f, bf);
  else if (m == 3)   wbf[dst] = rdbf(inp_w, (256 + t)*256 + f, bf);
  else if (m == 4)   wbf[dst] = rdbf(inp_w, (512 + t)*256 + f, bf);
  else if (m == 5)   wbf[dst] = rdbf(out_w, t*256 + f, bf);
  else if (f == 0) {
    ws[BIAS_OFF + t]        = ldin(lin_b, t, bf);
    ws[BIAS_OFF + 256 + t]  = ldin(inp_b, t, bf);
    ws[BIAS_OFF + 512 + t]  = ldin(inp_b, 256 + t, bf);
    ws[BIAS_OFF + 768 + t]  = ldin(inp_b, 512 + t, bf);
    ws[BIAS_OFF + 1024 + t] = ldin(out_b, t, bf);
    ws[BIAS_OFF + 1280 + t] = ldin(a1, t, bf);
    ws[BIAS_OFF + 1536 + t] = ldin(a2, t, bf);
  }
}

// -------- Wh = x @ Wcat -> WhT bf16 [h][b][d][n]; s1/s2 head reductions ----
__global__ __launch_bounds__(256) void whs_kernel(const void* x, float* ws,
                                                  const int* flagp) {
  const int bf = *flagp;
  int t = threadIdx.x;
  int r0 = blockIdx.x * 8;
  __shared__ __align__(16) float U[8][256];
  #pragma unroll
  for (int r = 0; r < 8; ++r)
    U[r][t] = ldin(x, (long)(r0 + r)*256 + t, bf);
  __syncthreads();
  const ushort4* w4 = (const ushort4*)ws;
  float acc[8] = {0,0,0,0,0,0,0,0};
  for (int e4 = 0; e4 < 64; ++e4) {
    ushort4 u = w4[e4*256 + t];
    float w0 = bf2f(u.x), w1 = bf2f(u.y), w2 = bf2f(u.z), w3 = bf2f(u.w);
    #pragma unroll
    for (int r = 0; r < 8; ++r) {
      float4 uu = *(const float4*)&U[r][e4*4];
      acc[r] += uu.x*w0 + uu.y*w1 + uu.z*w2 + uu.w*w3;
    }
  }
  int h = t >> 5, d = t & 31;
  float a1v = ws[BIAS_OFF + 1280 + t];
  float a2v = ws[BIAS_OFF + 1536 + t];
  unsigned short wvals[8];
  #pragma unroll
  for (int r = 0; r < 8; ++r) {
    int row = r0 + r;
    wvals[r] = f2bf(acc[r]);
    float p1 = acc[r]*a1v, p2 = acc[r]*a2v;
    #pragma unroll
    for (int off = 16; off > 0; off >>= 1) {
      p1 += __shfl_xor(p1, off, 32);
      p2 += __shfl_xor(p2, off, 32);
    }
    if (d == 0) {
      ws[S1_OFF + h*4096 + row] = p1;
      ws[S2_OFF + h*4096 + row] = p2;
    }
  }
  // WhT[h][b][d][n], 8 contiguous n per thread (16B store)
  {
    unsigned short* wht = (unsigned short*)(ws + A_OFF);
    int bb = r0 >> 10, nn = r0 & 1023;
    *(bf16x8s*)(wht + ((long)((h*4 + bb)*32 + d))*1024 + nn) = *(bf16x8s*)wvals;
  }
}

// ------- graph attention + residual + fused rownorm; e_out = mean_h attn ---
// 1-D grid (1024), XCD-swizzled: low 3 bits = (b*2 + n0-parity).
// Scores+softmax register-resident (s2 read straight from L2; s1 wave-uniform);
// P stored bf16 in Pb; PV via mfma_f32_16x16x32_bf16 against WhT.
// PB_S = 1056 ushorts = 528 words, 528 % 32 == 16: the 16 unique (row,quad)
// b128 A-frag addresses land 2-per-4-bank-group (2-way = free; 1032 gave
// 4-way -> the R13 2.16M SQ_LDS_BANK_CONFLICT). 2 barriers/head.
#define PB_S 1056
__global__ __launch_bounds__(256) void attn1_kernel(const void* x, const int* adj,
                                                    float* ws, void* dout,
                                                    const int* flagp) {
  const int bf = *flagp;
  int t = threadIdx.x;
  int gid = blockIdx.x;
  int b = (gid >> 1) & 3;
  int n0 = ((((gid >> 3) << 1) | (gid & 1))) * 4;
  __shared__ unsigned char adjm[4][1024];
  __shared__ __align__(16) unsigned short Pb[4][PB_S];
  __shared__ __align__(16) float opart[4][4][16];
  __shared__ __align__(16) float xrow[4][256];
  for (int r = 0; r < 4; ++r) {
    int base = (b*1024 + n0 + r) * 1024;
    for (int j = 0; j < 4; ++j) {
      int m = t + 256*j;
      adjm[r][m] = (adj[base + m] > 0) ? 1 : 0;
    }
  }
  int w = t >> 6, lane = t & 63;
  int fm = lane & 15, quad = lane >> 4;
  float eacc[16];
  #pragma unroll
  for (int j = 0; j < 16; ++j) eacc[j] = 0.0f;
  const unsigned short* wht = (const unsigned short*)(ws + A_OFF);
  __syncthreads();
  for (int h = 0; h < 8; ++h) {
    // scores + softmax in registers: wave w owns row w; s2 straight from L2
    {
      float s1v = ws[S1_OFF + h*4096 + b*1024 + n0 + w];
      const float* s2p = ws + S2_OFF + h*4096 + b*1024;
      float p[16];
      float mx = -3.4e38f;
      #pragma unroll
      for (int j = 0; j < 16; ++j) {
        int m = lane + 64*j;
        float ev = s1v + s2p[m];
        ev = (ev >= 0.0f) ? ev : 0.1f*ev;
        ev = adjm[w][m] ? ev : NEGC;
        p[j] = ev;
        mx = fmaxf(mx, ev);
      }
      #pragma unroll
      for (int off = 32; off > 0; off >>= 1) mx = fmaxf(mx, __shfl_xor(mx, off));
      float s = 0.0f;
      #pragma unroll
      for (int j = 0; j < 16; ++j) { p[j] = __expf(p[j] - mx); s += p[j]; }
      #pragma unroll
      for (int off = 32; off > 0; off >>= 1) s += __shfl_xor(s, off);
      float rs = 1.0f / s;
      #pragma unroll
      for (int j = 0; j < 16; ++j) {
        float pv = p[j] * rs;
        Pb[w][lane + 64*j] = f2bf(pv);
        eacc[j] += 0.125f * pv;
      }
    }
    __syncthreads();
    // PV via MFMA: wave w -> ntile (w&1), k-tiles (w>>1)*16 .. +15
    {
      int ntile = w & 1;
      int ktbase = (w >> 1) * 16;
      int vd = ntile*16 + fm;
      const unsigned short* wrow = wht + ((long)((h*4 + b)*32 + vd))*1024;
      f32x4 acc = {0.0f, 0.0f, 0.0f, 0.0f};
      #pragma unroll
      for (int kt2 = 0; kt2 < 16; ++kt2) {
        int kt = ktbase + kt2;
        bf16x8s ap = *(const bf16x8s*)&Pb[fm & 3][kt*32 + quad*8];
        bf16x8s bw = *(const bf16x8s*)(wrow + kt*32 + quad*8);
        acc = __builtin_amdgcn_mfma_f32_16x16x32_bf16(ap, bw, acc, 0, 0, 0);
      }
      if (quad == 0) {            // D rows 0..3 are the real query rows
        #pragma unroll
        for (int i = 0; i < 4; ++i) opart[w][i][fm] = acc[i];
      }
    }
    __syncthreads();              // opart ready; Pb free for next head
    if (t < 128) {
      int r = t >> 5, dd = t & 31;
      int nt = dd >> 4, c = dd & 15;
      float sum = opart[nt][r][c] + opart[nt + 2][r][c];
      float hv = (sum >= 0.0f) ? sum : 0.01f*sum;
      long idx = (long)(b*1024 + n0 + r)*256 + h*32 + dd;
      xrow[r][h*32 + dd] = ldin(x, idx, bf) + hv;
    }
    // no barrier: next head's Pb/opart writes are fenced by the barriers above
  }
  __syncthreads();                // xrow complete
  // fused rownorm (ddof=1): wave w handles row w
  float vals[4]; float s = 0.0f;
  #pragma unroll
  for (int j = 0; j < 4; ++j) { vals[j] = xrow[w][lane + 64*j]; s += vals[j]; }
  #pragma unroll
  for (int off = 32; off > 0; off >>= 1) s += __shfl_xor(s, off);
  float mean = s * (1.0f/256.0f);
  float ss = 0.0f;
  #pragma unroll
  for (int j = 0; j < 4; ++j) { float d = vals[j] - mean; ss += d*d; }
  #pragma unroll
  for (int off = 32; off > 0; off >>= 1) ss += __shfl_xor(ss, off);
  float inv = 1.0f / (sqrtf(ss * (1.0f/255.0f)) + 1e-6f);
  float* Bp = ws + B_OFF + (b*1024 + n0 + w)*256;
  #pragma unroll
  for (int j = 0; j < 4; ++j) Bp[lane + 64*j] = (vals[j] - mean) * inv;
  // e_out: wave w writes row w from registers
  {
    long base = 1048576L + (long)(b*1024 + n0 + w)*1024;
    #pragma unroll
    for (int j = 0; j < 16; ++j)
      stout(dout, base + lane + 64*j, eacc[j], bf);
  }
}

// ---------------- column (axis=1) stats, ddof=1 ----------------------------
__global__ __launch_bounds__(256) void colstatsA_kernel(const float* in, float* cs) {
  int t = threadIdx.x;
  int j = blockIdx.x & 15;
  int b = blockIdx.x >> 4;
  float s = 0, ss = 0;
  for (int n = j*64; n < j*64 + 64; ++n) {
    float v = in[(b*1024 + n)*256 + t];
    s += v; ss += v*v;
  }
  cs[(b*16 + j)*256 + t] = s;
  cs[16384 + (b*16 + j)*256 + t] = ss;
}

__global__ __launch_bounds__(256) void colstatsB_kernel(const float* cs, float* st) {
  int t = threadIdx.x;
  int b = blockIdx.x;
  float s = 0, ss = 0;
  for (int j = 0; j < 16; ++j) {
    s  += cs[(b*16 + j)*256 + t];
    ss += cs[16384 + (b*16 + j)*256 + t];
  }
  float mean = s * (1.0f/1024.0f);
  float var = fmaxf((ss - s*mean) * (1.0f/1023.0f), 0.0f);
  st[b*256 + t] = mean;
  st[1024 + b*256 + t] = 1.0f / (sqrtf(var) + 1e-6f);
}

// ---------------- row GEMM, bf16 quad weights ------------------------------
// IN_MODE 0: plain fp32 [row][256]; 1: fp32 + colnorm(st); 2: float-input src
//   permuted (n,b,e)->(b,n,e); 3: fp32 head-major [b][h][n][32]
// RN 1: fused rownorm on output
// OUTM 0: fp32 [row][256]; 1: d_out (dtype per flag); 2: fp32 head-major;
//      3: bf16 head-major; 4: bf16 TRANSPOSED head-major [b][h][d][n]
template<int IN_MODE, int RN, int OUTM>
__global__ __launch_bounds__(256) void gemm_kernel(const void* inp,
    const unsigned short* wmat, const float* bias, const float* st, void* outp,
    const int* flagp) {
  const int bf = *flagp;
  int t = threadIdx.x;
  int r0 = blockIdx.x * 8;
  __shared__ __align__(16) float U[8][256];
  #pragma unroll
  for (int r = 0; r < 8; ++r) {
    int row = r0 + r;
    float v;
    if (IN_MODE == 0) {
      v = ((const float*)inp)[row*256 + t];
    } else if (IN_MODE == 1) {
      int b = row >> 10;
      v = (((const float*)inp)[row*256 + t] - st[b*256 + t]) * st[1024 + b*256 + t];
    } else if (IN_MODE == 2) {
      int b = row >> 10, n = row & 1023;
      v = ldin(inp, (long)(n*4 + b)*256 + t, bf);
    } else {
      int b = row >> 10, n = row & 1023;
      v = ((const float*)inp)[((b*8 + (t >> 5))*1024 + n)*32 + (t & 31)];
    }
    U[r][t] = v;
  }
  __syncthreads();
  float bv = bias[t];
  float acc[8];
  #pragma unroll
  for (int r = 0; r < 8; ++r) acc[r] = bv;
  const ushort4* w4 = (const ushort4*)wmat;
  for (int e4 = 0; e4 < 64; ++e4) {
    ushort4 u = w4[e4*256 + t];
    float w0 = bf2f(u.x), w1 = bf2f(u.y), w2 = bf2f(u.z), w3 = bf2f(u.w);
    #pragma unroll
    for (int r = 0; r < 8; ++r) {
      float4 uu = *(const float4*)&U[r][e4*4];
      acc[r] += uu.x*w0 + uu.y*w1 + uu.z*w2 + uu.w*w3;
    }
  }
  if (RN == 0) {
    #pragma unroll
    for (int r = 0; r < 8; ++r) {
      int row = r0 + r;
      if (OUTM == 0) ((float*)outp)[row*256 + t] = acc[r];
      else if (OUTM == 1) stout(outp, (long)row*256 + t, acc[r], bf);
      else if (OUTM == 2) {
        int b = row >> 10, n = row & 1023;
        ((float*)outp)[((b*8 + (t >> 5))*1024 + n)*32 + (t & 31)] = acc[r];
      } else if (OUTM == 3) {
        int b = row >> 10, n = row & 1023;
        ((unsigned short*)outp)[((b*8 + (t >> 5))*1024 + n)*32 + (t & 31)] = f2bf(acc[r]);
      } else {
        int b = row >> 10, n = row & 1023;
        ((unsigned short*)outp)[((b*8 + (t >> 5))*32 + (t & 31))*1024 + n] = f2bf(acc[r]);
      }
    }
  } else {
    __syncthreads();
    #pragma unroll
    for (int r = 0; r < 8; ++r) U[r][t] = acc[r];
    __syncthreads();
    int w = t >> 6, lane = t & 63;
    for (int rr = w; rr < 8; rr += 4) {
      float vals[4]; float s = 0.0f;
      #pragma unroll
      for (int j = 0; j < 4; ++j) { vals[j] = U[rr][lane + 64*j]; s += vals[j]; }
      #pragma unroll
      for (int off = 32; off > 0; off >>= 1) s += __shfl_xor(s, off);
      float mean = s * (1.0f/256.0f);
      float ss = 0.0f;
      #pragma unroll
      for (int j = 0; j < 4; ++j) { float d = vals[j] - mean; ss += d*d; }
      #pragma unroll
      for (int off = 32; off > 0; off >>= 1) ss += __shfl_xor(ss, off);
      float inv = 1.0f / (sqrtf(ss * (1.0f/255.0f)) + 1e-6f);
      #pragma unroll
      for (int j = 0; j < 4; ++j)
        ((float*)outp)[(r0 + rr)*256 + lane + 64*j] = (vals[j] - mean) * inv;
    }
  }
}

// ---------------- MHA via MFMA, bf16 K/V, 8 q-rows per block ---------------
// GRID MUST BE 4096: 128 row-groups x 4 b x 8 h. h in low 3 bits (XCD-L2).
// Q fp32 head-major [b][h][n][32] at A_OFF (o overwrites q, exclusive slots);
// K bf16 [b][h][n][32] at B_OFF; V^T bf16 [b][h][d][n] at C_OFF.
// mfma_f32_16x16x32_bf16 layouts (m89-verified):
//   A[m=lane&15][k=(lane>>4)*8+j]; B[k=(lane>>4)*8+j][n=lane&15];
//   D col=lane&15, row=(lane>>4)*4+i.
#define SP_CS 36
#define SP_RS 1156
__global__ __launch_bounds__(256) void attn2_kernel(float* ws) {
  int t = threadIdx.x;
  int gid = blockIdx.x;
  int h = gid & 7;
  int b = (gid >> 3) & 3;
  int n0 = (gid >> 5) << 3;   // 8 q-rows per block; gid>>5 in 0..127
  __shared__ __align__(16) float Sp[8*SP_RS];
  __shared__ __align__(16) float opart[4][8][16];
  float* qq = ws + A_OFF;
  const unsigned short* kk = (const unsigned short*)(ws + B_OFF);
  const unsigned short* vt = (const unsigned short*)(ws + C_OFF);
  int base_bh = (b*8 + h)*1024;
  int w = t >> 6, lane = t & 63;
  int m = lane & 15, quad = lane >> 4;
  const float scl = 0.17677669529663687f; // 1/sqrt(32)
  // ---- QK via MFMA: wave w covers keys w*256 .. +255 ----------------------
  {
    const float* qp = qq + (base_bh + n0 + (lane & 7))*32 + quad*8;
    bf16x8s aq;
    #pragma unroll
    for (int j = 0; j < 8; ++j) ((unsigned short*)&aq)[j] = f2bf(qp[j]);
    f32x4 zero = {0.0f, 0.0f, 0.0f, 0.0f};
    #pragma unroll
    for (int kt = 0; kt < 16; ++kt) {
      int kbase = w*256 + kt*16;
      bf16x8s bk = *(const bf16x8s*)(kk + (base_bh + kbase + m)*32 + quad*8);
      f32x4 d = __builtin_amdgcn_mfma_f32_16x16x32_bf16(aq, bk, zero, 0, 0, 0);
      if (lane < 32) {
        int key = kbase + m;
        int a = (key >> 5)*SP_CS + (key & 31);
        #pragma unroll
        for (int i = 0; i < 4; ++i)
          Sp[(quad*4 + i)*SP_RS + a] = d[i] * scl;
      }
    }
  }
  __syncthreads();
  // ---- softmax: wave w handles rows w and w+4 -----------------------------
  #pragma unroll
  for (int rr = 0; rr < 2; ++rr) {
    float* Sr = Sp + (w + 4*rr)*SP_RS;
    float mx = -3.4e38f;
    #pragma unroll
    for (int j = 0; j < 16; ++j) {
      int mm = lane + 64*j;
      mx = fmaxf(mx, Sr[(mm >> 5)*SP_CS + (mm & 31)]);
    }
    #pragma unroll
    for (int off = 32; off > 0; off >>= 1) mx = fmaxf(mx, __shfl_xor(mx, off));
    float s = 0.0f;
    #pragma unroll
    for (int j = 0; j < 16; ++j) {
      int mm = lane + 64*j;
      int a = (mm >> 5)*SP_CS + (mm & 31);
      float p = __expf(Sr[a] - mx);
      Sr[a] = p;
      s += p;
    }
    #pragma unroll
    for (int off = 32; off > 0; off >>= 1) s += __shfl_xor(s, off);
    float rs = 1.0f / s;
    #pragma unroll
    for (int j = 0; j < 16; ++j) {
      int mm = lane + 64*j;
      Sr[(mm >> 5)*SP_CS + (mm & 31)] *= rs;
    }
  }
  __syncthreads();
  // ---- PV via MFMA: wave w -> N-tile (w&1), k-tiles (w>>1)*16 .. +15 ------
  {
    int ntile = w & 1;
    int ktbase = (w >> 1) * 16;
    int vd = ntile*16 + m;
    const unsigned short* vrow = vt + base_bh*32 + vd*1024;
    f32x4 acc = {0.0f, 0.0f, 0.0f, 0.0f};
    #pragma unroll
    for (int kt2 = 0; kt2 < 16; ++kt2) {
      int kt = ktbase + kt2;
      const float* pp = Sp + (lane & 7)*SP_RS + kt*SP_CS + quad*8;
      bf16x8s ap;
      #pragma unroll
      for (int j = 0; j < 8; ++j) ((unsigned short*)&ap)[j] = f2bf(pp[j]);
      bf16x8s bv = *(const bf16x8s*)(vrow + kt*32 + quad*8);
      acc = __builtin_amdgcn_mfma_f32_16x16x32_bf16(ap, bv, acc, 0, 0, 0);
    }
    if (lane < 32) {
      #pragma unroll
      for (int i = 0; i < 4; ++i)
        opart[w][quad*4 + i][m] = acc[i];
    }
  }
  __syncthreads();
  {
    int r = t >> 5, d = t & 31;
    int nt = d >> 4, c = d & 15;
    float sum = opart[nt][r][c] + opart[nt + 2][r][c];
    qq[(base_bh + n0 + r)*32 + d] = sum;   // o over q (own slots)
  }
}

extern "C" void kernel_launch(void* const* d_in, const int* in_sizes, int n_in,
                              void* d_out, int out_size, void* d_ws, size_t ws_size,
                              hipStream_t stream) {
  const void* x   = d_in[0];
  const void* src = d_in[1];
  const int* adj  = (const int*)d_in[2];
  const void* wg  = d_in[3];
  const void* a1  = d_in[4];
  const void* a2  = d_in[5];
  const void* lw  = d_in[6];
  const void* lb  = d_in[7];
  const void* ipw = d_in[8];
  const void* ipb = d_in[9];
  const void* opw = d_in[10];
  const void* opb = d_in[11];
  float* ws = (float*)d_ws;
  const unsigned short* wbf = (const unsigned short*)d_ws;
  int* flagp = (int*)(ws + FLAG_F);

  detect_kernel<<<1, 64, 0, stream>>>((const unsigned short*)x, flagp);
  prep_kernel<<<dim3(256, 7), 256, 0, stream>>>(wg, lw, ipw, opw, lb, ipb, opb,
                                                a1, a2, ws, flagp);
  whs_kernel<<<512, 256, 0, stream>>>(x, ws, flagp);
  attn1_kernel<<<1024, 256, 0, stream>>>(x, adj, ws, d_out, flagp);
  colstatsA_kernel<<<64, 256, 0, stream>>>(ws + B_OFF, ws + CS_OFF);
  colstatsB_kernel<<<4, 256, 0, stream>>>(ws + CS_OFF, ws + ST1_OFF);
  gemm_kernel<1,1,0><<<512, 256, 0, stream>>>(ws + B_OFF, wbf + 1*65536,
      ws + BIAS_OFF, ws + ST1_OFF, ws + C_OFF, flagp);
  colstatsA_kernel<<<64, 256, 0, stream>>>(ws + C_OFF, ws + CS_OFF);
  colstatsB_kernel<<<4, 256, 0, stream>>>(ws + CS_OFF, ws + ST2_OFF);
  gemm_kernel<1,0,2><<<512, 256, 0, stream>>>(ws + C_OFF, wbf + 2*65536,
      ws + BIAS_OFF + 256, ws + ST2_OFF, ws + A_OFF, flagp);   // Q fp32 hm
  gemm_kernel<1,0,3><<<512, 256, 0, stream>>>(ws + C_OFF, wbf + 3*65536,
      ws + BIAS_OFF + 512, ws + ST2_OFF, ws + B_OFF, flagp);   // K bf16 hm
  gemm_kernel<2,0,4><<<512, 256, 0, stream>>>(src, wbf + 4*65536,
      ws + BIAS_OFF + 768, nullptr, ws + C_OFF, flagp);        // V^T bf16 hm
  attn2_kernel<<<4096, 256, 0, stream>>>(ws);                  // o -> A_OFF
  gemm_kernel<3,0,1><<<512, 256, 0, stream>>>(ws + A_OFF, wbf + 5*65536,
      ws + BIAS_OFF + 1024, nullptr, d_out, flagp);            // out-proj
}